// Round 2
// baseline (5538.028 us; speedup 1.0000x reference)
//
#include <hip/hip_runtime.h>
#include <math.h>

#define Bn 16
#define Hn 256
#define Wn 256
#define Cn 64
#define Mk 12
#define NM 24
#define FCH 128

__device__ __forceinline__ float gelu_exact(float x) {
    return 0.5f * x * (1.0f + erff(x * 0.7071067811865476f));
}

// ---------------- tables ----------------
__global__ __launch_bounds__(256) void k_init_tables(float* tab_c, float* tab_s,
                                                     float* twc, float* tws) {
    int i = threadIdx.x;  // 0..255
    const float step = 0.024543692606170259f;  // 2*pi/256
    tab_c[i] = cosf(i * step);
    tab_s[i] = sinf(i * step);
    for (int ky = 0; ky < Mk; ++ky) {
        int idx = (i * ky) & 255;
        twc[i * Mk + ky] = cosf(idx * step);
        tws[i * Mk + ky] = sinf(idx * step);
    }
}

__global__ __launch_bounds__(256) void k_transpose_fc1(const float* __restrict__ fc1w,
                                                       float* __restrict__ fc1T) {
    int t = blockIdx.x * blockDim.x + threadIdx.x;  // < 8192
    int d = t % FCH, c = t / FCH;
    fc1T[d * Cn + c] = fc1w[c * FCH + d];
}

// ---------------- lift: x[b0.., H, W] -> h[bc,C,H,W] ----------------
__global__ __launch_bounds__(256) void k_lift(const float* __restrict__ x,
                                              const float* __restrict__ w0,
                                              const float* __restrict__ b0,
                                              float* __restrict__ h0) {
    int t = blockIdx.x * blockDim.x + threadIdx.x;  // < bc*1048576
    int w4 = t & 63;
    int hh = (t >> 6) & 255;
    int c  = (t >> 14) & 63;
    int b  = t >> 20;  // local batch
    float4 xv = ((const float4*)(x + (b * Hn + hh) * Wn))[w4];
    float sc = w0[c], bi = b0[c];
    float4 o;
    o.x = xv.x * sc + bi; o.y = xv.y * sc + bi;
    o.z = xv.z * sc + bi; o.w = xv.w * sc + bi;
    ((float4*)(h0 + ((b * Cn + c) * Hn + hh) * Wn))[w4] = o;
}

// ---------------- DFT along W (12 ky modes), lane-per-row ----------------
__global__ __launch_bounds__(64) void k_dft_w(const float* __restrict__ h,
                                              float* __restrict__ Xw,
                                              const float* __restrict__ twc,
                                              const float* __restrict__ tws) {
    int r = blockIdx.x * 64 + threadIdx.x;  // row in [0, bc*C*H)
    const float* hp = h + r * Wn;
    float xr[Mk], xi[Mk];
#pragma unroll
    for (int k = 0; k < Mk; ++k) { xr[k] = 0.f; xi[k] = 0.f; }
    for (int w4 = 0; w4 < 64; ++w4) {
        float4 v = ((const float4*)hp)[w4];
        float vv[4] = {v.x, v.y, v.z, v.w};
#pragma unroll
        for (int j = 0; j < 4; ++j) {
            int wbase = (w4 * 4 + j) * Mk;  // wave-uniform -> scalar loads
#pragma unroll
            for (int k = 0; k < Mk; ++k) {
                xr[k] += vv[j] * twc[wbase + k];
                xi[k] -= vv[j] * tws[wbase + k];
            }
        }
    }
    float* op = Xw + r * (2 * Mk);
#pragma unroll
    for (int k = 0; k < Mk; ++k) { op[2 * k] = xr[k]; op[2 * k + 1] = xi[k]; }
}

// ---------------- DFT along H (24 kx modes) ----------------
__global__ __launch_bounds__(256) void k_dft_h(const float* __restrict__ Xw,
                                               float* __restrict__ Xf,
                                               const float* __restrict__ tab_c,
                                               const float* __restrict__ tab_s) {
    int t = blockIdx.x * blockDim.x + threadIdx.x;  // < bc*18432
    int ky = t % Mk;
    int m  = (t / Mk) % NM;
    int i  = (t / (Mk * NM)) % Cn;
    int b  = t / (Mk * NM * Cn);
    int kx = (m < Mk) ? m : (232 + m);  // m>=12 -> kx = 244 + (m-12)
    const float* base = Xw + ((b * Cn + i) * Hn) * (2 * Mk) + 2 * ky;
    float ar = 0.f, ai = 0.f;
    for (int hh = 0; hh < Hn; ++hh) {
        float vr = base[hh * 2 * Mk];
        float vi = base[hh * 2 * Mk + 1];
        int idx = (kx * hh) & 255;
        float c = tab_c[idx], s = tab_s[idx];
        ar += vr * c + vi * s;   // * e^{-i theta}
        ai += vi * c - vr * s;
    }
    int ob = ((b * NM + m) * Mk + ky) * Cn + i;  // [b][m][ky][i]
    Xf[2 * ob] = ar; Xf[2 * ob + 1] = ai;
}

// ---------------- mode mixing: Z[b,o,m,ky] = sum_i Xf * W ----------------
__global__ __launch_bounds__(256) void k_mix(const float* __restrict__ Xf,
                                             const float* __restrict__ scw,
                                             float* __restrict__ Z, int l) {
    int t = blockIdx.x * blockDim.x + threadIdx.x;  // < bc*18432
    int o  = t % Cn;                                // lane = o (wave-uniform b,m,ky)
    int ky = (t / Cn) % Mk;
    int m  = (t / (Cn * Mk)) % NM;
    int b  = t / (Cn * Mk * NM);
    int j   = (m < Mk) ? 0 : 1;
    int kxw = (m < Mk) ? m : (m - Mk);
    const float* xb = Xf + (((b * NM + m) * Mk + ky) * Cn) * 2;  // uniform -> scalar
    const float* wb = scw + (((((l * 2 + j) * Cn + 0) * Cn + o) * Mk + kxw) * Mk + ky) * 2;
    const int wstride = Cn * Mk * Mk * 2;  // i stride = 18432
    float zr = 0.f, zi = 0.f;
    for (int i = 0; i < Cn; ++i) {
        float ar = xb[2 * i], ai = xb[2 * i + 1];
        float wr = wb[0], wi = wb[1];
        wb += wstride;
        zr += ar * wr - ai * wi;
        zi += ar * wi + ai * wr;
    }
    int ob = ((b * Cn + o) * NM + m) * Mk + ky;  // [b][o][m][ky]
    Z[2 * ob] = zr; Z[2 * ob + 1] = zi;
}

// ---------------- inverse DFT along H -> Y[b,o,hh,ky] ----------------
__global__ __launch_bounds__(256) void k_idft_h(const float* __restrict__ Z,
                                                float* __restrict__ Y,
                                                const float* __restrict__ tab_c,
                                                const float* __restrict__ tab_s) {
    int t = blockIdx.x * blockDim.x + threadIdx.x;  // < bc*196608
    int ky = t % Mk;
    int hh = (t / Mk) % Hn;
    int o  = (t / (Mk * Hn)) % Cn;
    int b  = t / (Mk * Hn * Cn);
    const float* zb = Z + ((b * Cn + o) * NM) * Mk * 2 + 2 * ky;
    float yr = 0.f, yi = 0.f;
#pragma unroll
    for (int m = 0; m < NM; ++m) {
        int kx = (m < Mk) ? m : (232 + m);
        int idx = (kx * hh) & 255;
        float c = tab_c[idx], s = tab_s[idx];
        float zr = zb[m * Mk * 2], zi = zb[m * Mk * 2 + 1];
        yr += zr * c - zi * s;   // * e^{+i theta}
        yi += zr * s + zi * c;
    }
    // fold 1/(H*W) and the hermitian factor 2 (ky=0 halved in consumer)
    const float scale = 2.0f / 65536.0f;
    int ob = ((b * Cn + o) * Hn + hh) * Mk + ky;
    Y[2 * ob] = yr * scale; Y[2 * ob + 1] = yi * scale;
}

// ------- fused: inverse DFT along W + pointwise conv + bias (+ gelu) -------
// NOTE: h and hn may alias (in-place). Safe: each thread reads only its own
// (b,hh,w) fiber and writes the same fiber, reads before writes in program
// order. No __restrict__ on h/hn so the compiler keeps that order.
__global__ __launch_bounds__(256) void k_fused(const float* h,
                                               const float* __restrict__ Y,
                                               const float* __restrict__ pww,
                                               const float* __restrict__ pwb,
                                               float* hn,
                                               int l, int apply_gelu) {
    int b  = blockIdx.x >> 8;
    int hh = blockIdx.x & 255;
    int w  = threadIdx.x;
    // cw[k] = cos(2 pi k w / 256), sw[k] = sin(...)
    float cw[Mk], sw[Mk];
    cw[0] = 1.f; sw[0] = 0.f;
    float s1, c1;
    __sincosf(w * 0.024543692606170259f, &s1, &c1);
#pragma unroll
    for (int k = 1; k < Mk; ++k) {
        float nc = cw[k - 1] * c1 - sw[k - 1] * s1;
        float ns = sw[k - 1] * c1 + cw[k - 1] * s1;
        cw[k] = nc; sw[k] = ns;
    }
    float acc[Cn];
    const float* Yb = Y + (b * Cn * Hn + hh) * (2 * Mk);
#pragma unroll
    for (int o = 0; o < Cn; ++o) {
        const float* Yp = Yb + o * (Hn * 2 * Mk);  // wave-uniform -> scalar loads
        float a = Yp[0] * 0.5f + pwb[l * Cn + o];
#pragma unroll
        for (int k = 1; k < Mk; ++k)
            a += Yp[2 * k] * cw[k] - Yp[2 * k + 1] * sw[k];
        acc[o] = a;
    }
    const float* hb = h + (b * Cn * Hn + hh) * Wn + w;
    const float* wwb = pww + l * Cn * Cn;
#pragma unroll 1
    for (int ic = 0; ic < 4; ++ic) {
        float v[16];
#pragma unroll
        for (int j2 = 0; j2 < 16; ++j2)
            v[j2] = hb[(ic * 16 + j2) * (Hn * Wn)];
#pragma unroll
        for (int o = 0; o < Cn; ++o) {
            const float* wr = wwb + o * Cn + ic * 16;  // uniform -> s_load_dwordx16
            float a = acc[o];
#pragma unroll
            for (int j2 = 0; j2 < 16; ++j2)
                a += v[j2] * wr[j2];
            acc[o] = a;
        }
    }
    float* ob = hn + (b * Cn * Hn + hh) * Wn + w;
    if (apply_gelu) {
#pragma unroll
        for (int o = 0; o < Cn; ++o)
            ob[o * (Hn * Wn)] = gelu_exact(acc[o]);
    } else {
#pragma unroll
        for (int o = 0; o < Cn; ++o)
            ob[o * (Hn * Wn)] = acc[o];
    }
}

// ---------------- final MLP: fc1 (gelu) + fc2 ----------------
__global__ __launch_bounds__(256) void k_final(const float* __restrict__ h,
                                               const float* __restrict__ fc1T,
                                               const float* __restrict__ fc1b,
                                               const float* __restrict__ fc2w,
                                               const float* __restrict__ fc2b,
                                               float* __restrict__ out) {
    int b  = blockIdx.x >> 8;
    int hh = blockIdx.x & 255;
    int w  = threadIdx.x;
    float hid[FCH];
#pragma unroll
    for (int d = 0; d < FCH; ++d) hid[d] = fc1b[d];
    const float* hb = h + (b * Cn * Hn + hh) * Wn + w;
#pragma unroll 1
    for (int ic = 0; ic < 4; ++ic) {
        float v[16];
#pragma unroll
        for (int j2 = 0; j2 < 16; ++j2)
            v[j2] = hb[(ic * 16 + j2) * (Hn * Wn)];
#pragma unroll
        for (int d = 0; d < FCH; ++d) {
            const float* wr = fc1T + d * Cn + ic * 16;  // uniform -> s_load
            float a = hid[d];
#pragma unroll
            for (int j2 = 0; j2 < 16; ++j2)
                a += v[j2] * wr[j2];
            hid[d] = a;
        }
    }
    float accv = fc2b[0];
#pragma unroll
    for (int d = 0; d < FCH; ++d)
        accv += gelu_exact(hid[d]) * fc2w[d];
    out[(b * Hn + hh) * Wn + w] = accv;
}

extern "C" void kernel_launch(void* const* d_in, const int* in_sizes, int n_in,
                              void* d_out, int out_size, void* d_ws, size_t ws_size,
                              hipStream_t stream) {
    const float* x    = (const float*)d_in[0];
    const float* fc0w = (const float*)d_in[1];
    const float* fc0b = (const float*)d_in[2];
    const float* scw  = (const float*)d_in[3];
    const float* pww  = (const float*)d_in[4];
    const float* pwb  = (const float*)d_in[5];
    const float* fc1w = (const float*)d_in[6];
    const float* fc1b = (const float*)d_in[7];
    const float* fc2w = (const float*)d_in[8];
    const float* fc2b = (const float*)d_in[9];
    float* out = (float*)d_out;
    float* ws  = (float*)d_ws;

    // Pick largest batch chunk bc that fits ws_size.
    // per-batch floats: h 4,194,304 | XwY 393,216 | Xf 36,864 | Zb 36,864
    // tables+fc1T: 14,848 floats
    const size_t perb = 4661248;
    const size_t tabf = 14848;
    int bc = 0;
    for (int cand = 16; cand >= 1; cand >>= 1) {
        if ((tabf + perb * (size_t)cand) * 4 <= ws_size) { bc = cand; break; }
    }
    if (bc == 0) return;  // diagnosable: zero output

    float* tabc = ws;             // 256
    float* tabs = tabc + 256;     // 256
    float* twc  = tabs + 256;     // 3072
    float* tws_ = twc + 3072;     // 3072
    float* fc1T = tws_ + 3072;    // 8192
    float* hbuf = ws + tabf;                  // bc*4,194,304
    float* XwY  = hbuf + (size_t)bc * 4194304;  // bc*393,216 (Xw and Y share)
    float* Xf   = XwY + (size_t)bc * 393216;    // bc*36,864
    float* Zb   = Xf + (size_t)bc * 36864;      // bc*36,864

    k_init_tables<<<1, 256, 0, stream>>>(tabc, tabs, twc, tws_);
    k_transpose_fc1<<<32, 256, 0, stream>>>(fc1w, fc1T);

    for (int b0 = 0; b0 < Bn; b0 += bc) {
        const float* xb = x + (size_t)b0 * Hn * Wn;
        float* outb = out + (size_t)b0 * Hn * Wn;
        k_lift<<<bc * 4096, 256, 0, stream>>>(xb, fc0w, fc0b, hbuf);
        for (int l = 0; l < 4; ++l) {
            k_dft_w<<<bc * 256, 64, 0, stream>>>(hbuf, XwY, twc, tws_);
            k_dft_h<<<bc * 72, 256, 0, stream>>>(XwY, Xf, tabc, tabs);
            k_mix<<<bc * 72, 256, 0, stream>>>(Xf, scw, Zb, l);
            k_idft_h<<<bc * 768, 256, 0, stream>>>(Zb, XwY, tabc, tabs);
            k_fused<<<bc * 256, 256, 0, stream>>>(hbuf, XwY, pww, pwb, hbuf, l,
                                                  (l < 3) ? 1 : 0);
        }
        k_final<<<bc * 256, 256, 0, stream>>>(hbuf, fc1T, fc1b, fc2w, fc2b, outb);
    }
}